// Round 5
// baseline (102.667 us; speedup 1.0000x reference)
//
#include <hip/hip_runtime.h>

typedef unsigned short u16;
typedef float f32x4 __attribute__((ext_vector_type(4)));
typedef float f32x16 __attribute__((ext_vector_type(16)));
typedef __bf16 bf16x8 __attribute__((ext_vector_type(8)));

#define MFMA16(a, b, c) __builtin_amdgcn_mfma_f32_16x16x32_bf16((a), (b), (c), 0, 0, 0)
#define MFMA32(a, b, c) __builtin_amdgcn_mfma_f32_32x32x16_bf16((a), (b), (c), 0, 0, 0)

#define B_ 8
#define H_ 8
#define S_ 1024

__device__ __forceinline__ u16 f2bf(float f) {
  unsigned u = __float_as_uint(f);
  return (u16)((u + 0x7fffu + ((u >> 16) & 1u)) >> 16);
}
// pack 2 f32 -> 2 bf16 in one instr (dst.lo = a, dst.hi = b)
__device__ __forceinline__ unsigned cvtpk(float a, float b) {
  unsigned r;
  asm("v_cvt_pk_bf16_f32 %0, %1, %2" : "=v"(r) : "v"(a), "v"(b));
  return r;
}
// after: a = [a_lo | b_lo], b = [a_hi | b_hi]  (32-lane half swap)
__device__ __forceinline__ void plswap(unsigned& a, unsigned& b) {
  asm("v_permlane32_swap_b32 %0, %1" : "+v"(a), "+v"(b));
}
// async global->LDS, 16B per lane. LDS dest = wave-uniform base + lane*16.
__device__ __forceinline__ void gload16(const void* g, void* l) {
  __builtin_amdgcn_global_load_lds((__attribute__((address_space(1))) const void*)g,
                                   (__attribute__((address_space(3))) void*)l, 16, 0, 0);
}

// ---------------- all fp32->bf16 converts in one dispatch ----------------
__global__ void __launch_bounds__(256) convAll(const float* __restrict__ q, const float* __restrict__ k,
                                               const float* __restrict__ v, const float* __restrict__ Wq,
                                               const float* __restrict__ Wk, const float* __restrict__ Wv,
                                               const float* __restrict__ Wo, const float* __restrict__ relk,
                                               u16* __restrict__ dq, u16* __restrict__ dk, u16* __restrict__ dv,
                                               u16* __restrict__ dWq, u16* __restrict__ dWk, u16* __restrict__ dWv,
                                               u16* __restrict__ dWo, u16* __restrict__ drelk) {
  const int bid = blockIdx.x;
  const float* s; u16* d; size_t off;
  if (bid < 12288) {
    size_t i4 = (size_t)bid * 256 + threadIdx.x;   // 3*1048576 float4s
    int tsel = (int)(i4 >> 20);
    off = (i4 & 1048575) << 2;
    s = tsel == 0 ? q : (tsel == 1 ? k : v);
    d = tsel == 0 ? dq : (tsel == 1 ? dk : dv);
  } else {
    size_t i = ((size_t)(bid - 12288) * 256 + threadIdx.x) << 2;
    if (i >= 1050688) return; // 4*262144 + 33*64
    if (i < 262144)       { s = Wq; d = dWq; off = i; }
    else if (i < 524288)  { s = Wk; d = dWk; off = i - 262144; }
    else if (i < 786432)  { s = Wv; d = dWv; off = i - 524288; }
    else if (i < 1048576) { s = Wo; d = dWo; off = i - 786432; }
    else                  { s = relk; d = drelk; off = i - 1048576; }
  }
  float4 f = *(const float4*)(s + off);
  uint2 o;
  o.x = cvtpk(f.x, f.y);
  o.y = cvtpk(f.z, f.w);
  *(uint2*)(d + off) = o;
}

// ---------------- fused Q/K/V projection GEMM (768 blocks) ----------------
// seg 0: Q -> bf16 head-split [B,H,S,64]; seg 1: K same; seg 2: V -> transposed [B*H,64,S].
__global__ void __launch_bounds__(256) qkv_gemm(const u16* __restrict__ Xq, const u16* __restrict__ Xk,
                                                const u16* __restrict__ Xv, const u16* __restrict__ Wqb,
                                                const u16* __restrict__ Wkb, const u16* __restrict__ Wvb,
                                                const float* __restrict__ bq, const float* __restrict__ bk,
                                                const float* __restrict__ bv, u16* __restrict__ Qh,
                                                u16* __restrict__ Kh, u16* __restrict__ Vt) {
  __shared__ u16 As[128 * 64];
  __shared__ u16 Bs[128 * 64];
  const int seg = blockIdx.x >> 8, bid = blockIdx.x & 255;
  const u16* A = seg == 0 ? Xq : (seg == 1 ? Xk : Xv);
  const u16* W = seg == 0 ? Wqb : (seg == 1 ? Wkb : Wvb);
  const float* bias = seg == 0 ? bq : (seg == 1 ? bk : bv);
  const int tid = threadIdx.x, lane = tid & 63, wid = tid >> 6;
  const int c = lane & 15, g = lane >> 4;
  const int bm = bid >> 2, bn = bid & 3;
  const int m0 = bm << 7, n0 = bn << 7;
  const int wrow = (wid >> 1) << 6, wcol = (wid & 1) << 6;

  const f32x4 ZF = {0.f, 0.f, 0.f, 0.f};
  f32x4 acc[4][4];
#pragma unroll
  for (int i = 0; i < 4; ++i)
#pragma unroll
    for (int j = 0; j < 4; ++j) acc[i][j] = ZF;

  for (int kt = 0; kt < 512; kt += 64) {
    __syncthreads();
#pragma unroll
    for (int i = 0; i < 4; ++i) {
      int Lb = ((wid << 2) | i) << 10;
      int L = Lb + lane * 16;
      int row = L >> 7;                                 // 0..127
      int off = (L & 127) ^ ((row & 7) << 4);           // pre-swizzled source
      gload16((const char*)A + ((((size_t)(m0 + row)) << 9) + kt) * 2 + off, (char*)As + Lb);
      gload16((const char*)W + ((((size_t)(n0 + row)) << 9) + kt) * 2 + off, (char*)Bs + Lb);
    }
    __syncthreads();
#pragma unroll
    for (int kk = 0; kk < 2; ++kk) {
      bf16x8 af[4], bfr[4];
#pragma unroll
      for (int rt = 0; rt < 4; ++rt) {
        int row = wrow + (rt << 4) + c;
        af[rt] = *(const bf16x8*)((const char*)As + row * 128 + (((kk << 6) | (g << 4)) ^ ((row & 7) << 4)));
      }
#pragma unroll
      for (int ct = 0; ct < 4; ++ct) {
        int row = wcol + (ct << 4) + c;
        bfr[ct] = *(const bf16x8*)((const char*)Bs + row * 128 + (((kk << 6) | (g << 4)) ^ ((row & 7) << 4)));
      }
#pragma unroll
      for (int rt = 0; rt < 4; ++rt)
#pragma unroll
        for (int ct = 0; ct < 4; ++ct) acc[rt][ct] = MFMA16(af[rt], bfr[ct], acc[rt][ct]);
    }
  }

#pragma unroll
  for (int rt = 0; rt < 4; ++rt)
#pragma unroll
    for (int ct = 0; ct < 4; ++ct) {
      int n = n0 + wcol + (ct << 4) + c;
      float bv2 = bias[n];
      if (seg == 2) {
        int b2 = m0 >> 10;
        int sbase = (m0 & 1023) + wrow + (rt << 4) + (g << 2);
        int h2 = n >> 6, d2 = n & 63;
        uint2 o;
        o.x = cvtpk(acc[rt][ct][0] + bv2, acc[rt][ct][1] + bv2);
        o.y = cvtpk(acc[rt][ct][2] + bv2, acc[rt][ct][3] + bv2);
        *(uint2*)(Vt + ((((size_t)((b2 << 3) + h2) << 6) + d2) << 10) + sbase) = o;
      } else {
        u16* out = seg == 0 ? Qh : Kh;
#pragma unroll
        for (int r = 0; r < 4; ++r) {
          int m = m0 + wrow + (rt << 4) + (g << 2) + r;
          int b = m >> 10, s = m & 1023, h = n >> 6, d = n & 63;
          out[(((((size_t)(b * H_ + h)) << 10) + s) << 6) + d] = f2bf(acc[rt][ct][r] + bv2);
        }
      }
    }
}

// ---------------- output GEMM: C fp32 [M][512] = A(bf16) @ W(bf16)^T + bias ----------------
__global__ void __launch_bounds__(256) gemm_out(const u16* __restrict__ A, const u16* __restrict__ W,
                                                const float* __restrict__ bias, float* __restrict__ out) {
  __shared__ u16 As[128 * 64];
  __shared__ u16 Bs[128 * 64];
  const int tid = threadIdx.x, lane = tid & 63, wid = tid >> 6;
  const int c = lane & 15, g = lane >> 4;
  const int bm = blockIdx.x >> 2, bn = blockIdx.x & 3;
  const int m0 = bm << 7, n0 = bn << 7;
  const int wrow = (wid >> 1) << 6, wcol = (wid & 1) << 6;

  const f32x4 ZF = {0.f, 0.f, 0.f, 0.f};
  f32x4 acc[4][4];
#pragma unroll
  for (int i = 0; i < 4; ++i)
#pragma unroll
    for (int j = 0; j < 4; ++j) acc[i][j] = ZF;

  for (int kt = 0; kt < 512; kt += 64) {
    __syncthreads();
#pragma unroll
    for (int i = 0; i < 4; ++i) {
      int Lb = ((wid << 2) | i) << 10;
      int L = Lb + lane * 16;
      int row = L >> 7;
      int off = (L & 127) ^ ((row & 7) << 4);
      gload16((const char*)A + ((((size_t)(m0 + row)) << 9) + kt) * 2 + off, (char*)As + Lb);
      gload16((const char*)W + ((((size_t)(n0 + row)) << 9) + kt) * 2 + off, (char*)Bs + Lb);
    }
    __syncthreads();
#pragma unroll
    for (int kk = 0; kk < 2; ++kk) {
      bf16x8 af[4], bfr[4];
#pragma unroll
      for (int rt = 0; rt < 4; ++rt) {
        int row = wrow + (rt << 4) + c;
        af[rt] = *(const bf16x8*)((const char*)As + row * 128 + (((kk << 6) | (g << 4)) ^ ((row & 7) << 4)));
      }
#pragma unroll
      for (int ct = 0; ct < 4; ++ct) {
        int row = wcol + (ct << 4) + c;
        bfr[ct] = *(const bf16x8*)((const char*)Bs + row * 128 + (((kk << 6) | (g << 4)) ^ ((row & 7) << 4)));
      }
#pragma unroll
      for (int rt = 0; rt < 4; ++rt)
#pragma unroll
        for (int ct = 0; ct < 4; ++ct) acc[rt][ct] = MFMA16(af[rt], bfr[ct], acc[rt][ct]);
    }
  }

#pragma unroll
  for (int rt = 0; rt < 4; ++rt)
#pragma unroll
    for (int ct = 0; ct < 4; ++ct) {
      int n = n0 + wcol + (ct << 4) + c;
      float bv = bias[n];
#pragma unroll
      for (int r = 0; r < 4; ++r) {
        int m = m0 + wrow + (rt << 4) + (g << 2) + r;
        out[(((size_t)m) << 9) + n] = acc[rt][ct][r] + bv;
      }
    }
}

// ---------------- flash attention: 32x32 MFMA, 32 q/wave, in-register P ----------------
// wave wid owns q = qbase + wid*32 + (lane&31); hi = lane>>5 splits k-rows.
__global__ void __launch_bounds__(256) flash_kernel(const u16* __restrict__ Qh, const u16* __restrict__ Kh,
                                                    const u16* __restrict__ Vt, const u16* __restrict__ relkb,
                                                    const float* __restrict__ relv, u16* __restrict__ Xout) {
  __shared__ u16 Ks[2][64 * 64];
  __shared__ u16 Vs[2][64 * 64];
  __shared__ float qrelS[128 * 33];   // exp2-domain bias; overlaid by rvT (bf16) in epilogue
  __shared__ u16 Pband[128 * 32];     // unnormalized band probs; slot 0 = low bucket
  __shared__ float rv32S[64];
  __shared__ float2 normS[128];       // {inv, hsum} per q

  const int tid = threadIdx.x, lane = tid & 63, wid = tid >> 6;
  const int c32 = lane & 31, hi = lane >> 5;
  // XCD swizzle: contiguous chunks per XCD
  const int swz = ((blockIdx.x & 7) << 6) | (blockIdx.x >> 3);
  const int bh = swz >> 3, qt = swz & 7;
  const int qbase = qt << 7;
  const size_t rowbase = ((size_t)bh) << 10;
  const int wavebase = wid << 5;
  const int qloc = wavebase + c32;
  const float K1 = 0.51013619f;   // (1/sqrt(8)) * log2(e)
  const float C0 = 24.0f;

#define STAGE(buf, kt_) do { \
    const int k64_ = (kt_) << 6; \
    _Pragma("unroll") \
    for (int i_ = 0; i_ < 2; ++i_) { \
      int Lb_ = ((wid << 1) | i_) << 10; \
      int L_ = Lb_ + lane * 16; \
      int row_ = L_ >> 7; \
      int off_ = (L_ & 127) ^ ((row_ & 7) << 4); \
      gload16((const char*)Kh + ((rowbase + k64_ + row_) << 7) + off_, (char*)Ks[buf] + Lb_); \
      gload16((const char*)Vt + ((((size_t)bh << 6) + row_) << 11) + (k64_ << 1) + off_, (char*)Vs[buf] + Lb_); \
    } \
  } while (0)

  STAGE(0, 0);

  // zero Pband (8192B) + rv32
  ((uint4*)Pband)[tid] = uint4{0, 0, 0, 0};
  ((uint4*)Pband)[tid + 256] = uint4{0, 0, 0, 0};
  if (tid < 64) rv32S[tid] = relv[2048 + tid];

  // ---- prologue: qrelS via 16x16 MFMAs (2 q-halves per wave) ----
  {
    const int c = lane & 15, g = lane >> 4;
    const f32x4 ZF4 = {0.f, 0.f, 0.f, 0.f};
#pragma unroll
    for (int hf = 0; hf < 2; ++hf) {
      const int q16 = wavebase + (hf << 4) + c;
      const u16* qp = Qh + ((rowbase + qbase + q16) << 6);
      bf16x8 qa0 = *(const bf16x8*)(qp + (g << 3));
      bf16x8 qa1 = *(const bf16x8*)(qp + 32 + (g << 3));
#pragma unroll
      for (int t = 0; t < 3; ++t) {
        int rr = t * 16 + c; if (rr > 32) rr = 32;
        f32x4 qr = ZF4;
        qr = MFMA16(*(const bf16x8*)(relkb + (rr << 6) + (g << 3)), qa0, qr);
        qr = MFMA16(*(const bf16x8*)(relkb + (rr << 6) + 32 + (g << 3)), qa1, qr);
#pragma unroll
        for (int j = 0; j < 4; ++j) {
          int r = t * 16 + (g << 2) + j;
          if (r < 33) qrelS[q16 * 33 + r] = qr[j] * K1 - C0;
        }
      }
    }
  }

  // main-loop Q B-fragments (col = own q, d-slice per ks/hi)
  bf16x8 qb[4];
  {
    const u16* qp = Qh + ((rowbase + qbase + qloc) << 6);
#pragma unroll
    for (int ks = 0; ks < 4; ++ks) qb[ks] = *(const bf16x8*)(qp + (ks << 4) + (hi << 3));
  }

  __syncthreads();   // STAGE(0), Pband, rv32S, qrelS all visible

  const float bias_lo = qrelS[qloc * 33 + 0];
  const float bias_hi = qrelS[qloc * 33 + 32];

  // hoisted LDS byte offsets for K/V fragment reads (same pattern both)
  int off2[2][4];
#pragma unroll
  for (int mt = 0; mt < 2; ++mt) {
    int row = (mt << 5) + c32;
#pragma unroll
    for (int ks = 0; ks < 4; ++ks)
      off2[mt][ks] = row * 128 + ((((ks << 5) | (hi << 4))) ^ ((row & 7) << 4));
  }

  const f32x16 Z16 = {0.f,0.f,0.f,0.f,0.f,0.f,0.f,0.f,0.f,0.f,0.f,0.f,0.f,0.f,0.f,0.f};
  f32x16 acc0 = Z16, acc1 = Z16;
  float lsum = 0.f, lowsum = 0.f, psum = 0.f;

  for (int kt = 0; kt < 16; ++kt) {
    const int cur = kt & 1;
    if (kt < 15) STAGE(cur ^ 1, kt + 1);   // prefetch into other buffer

    // QK^T swapped (A=K, B=Q): sA/sB = S[k-rows][q=own], k split by mt and crow(r,hi)
    f32x16 sA = Z16, sB = Z16;
#pragma unroll
    for (int ks = 0; ks < 4; ++ks) {
      bf16x8 ka0 = *(const bf16x8*)((const char*)Ks + (cur << 13) + off2[0][ks]);
      bf16x8 ka1 = *(const bf16x8*)((const char*)Ks + (cur << 13) + off2[1][ks]);
      sA = MFMA32(ka0, qb[ks], sA);
      sB = MFMA32(ka1, qb[ks], sB);
    }

    const int D0 = (kt << 6) - qbase;
    if (D0 >= 192) {            // all dlt >= 17: high bucket
      float t0 = 0.f;
#pragma unroll
      for (int r = 0; r < 16; ++r) {
        float pe = __builtin_amdgcn_exp2f(fmaf(sA[r], K1, bias_hi)); sA[r] = pe; t0 += pe;
        float pf = __builtin_amdgcn_exp2f(fmaf(sB[r], K1, bias_hi)); sB[r] = pf; t0 += pf;
      }
      lsum += t0;
    } else if (D0 <= -128) {    // all dlt <= -17: low bucket
      float t0 = 0.f;
#pragma unroll
      for (int r = 0; r < 16; ++r) {
        float pe = __builtin_amdgcn_exp2f(fmaf(sA[r], K1, bias_lo)); sA[r] = pe; t0 += pe;
        float pf = __builtin_amdgcn_exp2f(fmaf(sB[r], K1, bias_lo)); sB[r] = pf; t0 += pf;
      }
      lsum += t0; lowsum += t0;
    } else {                    // boundary tiles (<=4 of 16), wave-uniform branch
      const int base = D0 - qloc + (hi << 2);
#pragma unroll
      for (int mt = 0; mt < 2; ++mt) {
        f32x16& s = mt ? sB : sA;
#pragma unroll
        for (int r = 0; r < 16; ++r) {
          int dlt = base + (mt << 5) + (r & 3) + ((r >> 2) << 3);
          int idx = dlt < -16 ? 0 : (dlt > 16 ? 32 : dlt + 16);
          float pe = __builtin_amdgcn_exp2f(fmaf(s[r], K1, qrelS[qloc * 33 + idx]));
          s[r] = pe;
          lsum += pe;
          if (dlt <= -16) lowsum += pe;
          else if (dlt < 16) { psum += pe; Pband[(qloc << 5) + dlt + 16] = f2bf(pe); }
        }
      }
    }

    // P -> PV A-fragments, fully in-register: 16 cvt_pk + 8 permlane32_swap
    unsigned uA[8], uB[8];
#pragma unroll
    for (int j = 0; j < 8; ++j) {
      uA[j] = cvtpk(sA[2 * j], sA[2 * j + 1]);
      uB[j] = cvtpk(sB[2 * j], sB[2 * j + 1]);
    }
    bf16x8 pa[4];
#pragma unroll
    for (int ks = 0; ks < 4; ++ks) {
      int jb = (ks & 1) << 2;
      unsigned w0, w1, w2, w3;
      if (ks < 2) { w0 = uA[jb]; w2 = uA[jb + 2]; w1 = uA[jb + 1]; w3 = uA[jb + 3]; }
      else        { w0 = uB[jb]; w2 = uB[jb + 2]; w1 = uB[jb + 1]; w3 = uB[jb + 3]; }
      plswap(w0, w2);
      plswap(w1, w3);
      uint4 t4{w0, w1, w2, w3};
      pa[ks] = __builtin_bit_cast(bf16x8, t4);
    }

    // PV (A=P, B=V): acc[nt] cols d = nt*32 + c32, rows q = crow(r,hi)
#pragma unroll
    for (int ks = 0; ks < 4; ++ks) {
      bf16x8 vb0 = *(const bf16x8*)((const char*)Vs + (cur << 13) + off2[0][ks]);
      bf16x8 vb1 = *(const bf16x8*)((const char*)Vs + (cur << 13) + off2[1][ks]);
      acc0 = MFMA32(pa[ks], vb0, acc0);
      acc1 = MFMA32(pa[ks], vb1, acc1);
    }
    __syncthreads();   // drains prefetch + protects dbuf swap
  }

  // ---- epilogue ----
  lsum += __shfl_xor(lsum, 32);
  lowsum += __shfl_xor(lowsum, 32);
  psum += __shfl_xor(psum, 32);
  const float inv = 1.f / lsum;
  const float hsum = lsum - lowsum - psum;   // unnormalized high-bucket mass
  if (lane < 32) {
    Pband[qloc << 5] = f2bf(lowsum);
    normS[qloc] = float2{inv, hsum};
  }
  __syncthreads();
  // overlay rv^T (bf16 [64 d][32 r]) into dead qrelS
  u16* rvT = (u16*)qrelS;
  for (int i = tid; i < 2048; i += 256) rvT[i] = f2bf(relv[((i & 31) << 6) + (i >> 5)]);
  __syncthreads();

  // acc += Pband[q][r] * rvT[d][r]  (band + low), unnormalized
#pragma unroll
  for (int ks2 = 0; ks2 < 2; ++ks2) {
    bf16x8 pf = *(const bf16x8*)(Pband + (qloc << 5) + (ks2 << 4) + (hi << 3));
    bf16x8 rv0 = *(const bf16x8*)(rvT + (c32 << 5) + (ks2 << 4) + (hi << 3));
    bf16x8 rv1 = *(const bf16x8*)(rvT + ((32 + c32) << 5) + (ks2 << 4) + (hi << 3));
    acc0 = MFMA32(pf, rv0, acc0);
    acc1 = MFMA32(pf, rv1, acc1);
  }

  const int b = bh >> 3, h = bh & 7;
  const float rvA = rv32S[c32], rvB = rv32S[32 + c32];
#pragma unroll
  for (int r = 0; r < 16; ++r) {
    int qw = wavebase + (r & 3) + ((r >> 2) << 3) + (hi << 2);
    float2 nh = normS[qw];
    size_t orow = ((((size_t)b << 10) + (qbase + qw)) << 9) + (h << 6);
    Xout[orow + c32]      = f2bf((acc0[r] + nh.y * rvA) * nh.x);
    Xout[orow + 32 + c32] = f2bf((acc1[r] + nh.y * rvB) * nh.x);
  }
#undef STAGE
}

// ---------------- launch ----------------
extern "C" void kernel_launch(void* const* d_in, const int* in_sizes, int n_in,
                              void* d_out, int out_size, void* d_ws, size_t ws_size,
                              hipStream_t stream) {
  (void)in_sizes; (void)n_in; (void)out_size; (void)ws_size;
  const float* query = (const float*)d_in[0];
  const float* key   = (const float*)d_in[1];
  const float* value = (const float*)d_in[2];
  const float* Wq = (const float*)d_in[3];
  const float* bq = (const float*)d_in[4];
  const float* Wk = (const float*)d_in[5];
  const float* bk = (const float*)d_in[6];
  const float* Wv = (const float*)d_in[7];
  const float* bv = (const float*)d_in[8];
  const float* Wo = (const float*)d_in[9];
  const float* bo = (const float*)d_in[10];
  const float* relk = (const float*)d_in[11];
  const float* relv = (const float*)d_in[12];

  char* ws = (char*)d_ws;
  u16*   Xq    = (u16*)(ws + 0);
  u16*   Xk    = (u16*)(ws + 8388608);
  u16*   Xv    = (u16*)(ws + 16777216);
  u16*   Wqb   = (u16*)(ws + 25165824);
  u16*   Wkb   = (u16*)(ws + 25690112);
  u16*   Wvb   = (u16*)(ws + 26214400);
  u16*   Wob   = (u16*)(ws + 26738688);
  u16*   relkb = (u16*)(ws + 27262976);   // 33*64 bf16
  u16*   Qh    = (u16*)(ws + 27271168);
  u16*   Kh    = (u16*)(ws + 35659776);
  u16*   Vt    = (u16*)(ws + 52436992);
  u16*   Xout  = (u16*)(ws + 70262784);

  convAll<<<13315, 256, 0, stream>>>(query, key, value, Wq, Wk, Wv, Wo, relk,
                                     Xq, Xk, Xv, Wqb, Wkb, Wvb, Wob, relkb);
  qkv_gemm<<<768, 256, 0, stream>>>(Xq, Xk, Xv, Wqb, Wkb, Wvb, bq, bk, bv, Qh, Kh, Vt);
  flash_kernel<<<512, 256, 0, stream>>>(Qh, Kh, Vt, relkb, relv, Xout);
  gemm_out<<<256, 256, 0, stream>>>(Xout, Wob, bo, (float*)d_out);
}